// Round 1
// baseline (114.358 us; speedup 1.0000x reference)
//
#include <hip/hip_runtime.h>

// Problem constants (from reference): B=4, L=256, DM=256, DL=64, R=256, K=1,
// N_ITER=4, STEPSIZE=1.0, DAMPING=0.0, REG=1.0.
//
// Algebraic collapse (see session journal): with STEPSIZE=1 and DAMPING=0 the
// loop's cn_qz/cn_qy are frozen at softmax(x) and uniform(1/64); every
// iteration produces the identical q_z = x + F, so the output is ONE message
// pass:
//   qz   = valid * softmax(x, -1)                       (B*L, DM)
//   t[z] = sum_i qz[z,i,:]                              (B, DM)
//   wbar[l,d] = mean_c W[l,c,d]                         (2, R)
//   P[b,a]   = sum_{l,d} V[l,b,d]*wbar[l,d]*U[l,a,d]    (DM, DM)
//   out[z,i,a] = x[z,i,a] + valid_i * sum_b (t[z,b]-qz[z,i,b]) * P[b,a]

#define DMv 256
#define LLv 256
#define RRv 256
#define DLv 64

__global__ void k_wbar(const float* __restrict__ W, float* __restrict__ wbar) {
    int idx = blockIdx.x * 256 + threadIdx.x;   // 0..511
    int l = idx >> 8, d = idx & 255;
    const float* Wl = W + l * DLv * RRv;
    float s = 0.f;
#pragma unroll
    for (int c = 0; c < DLv; ++c) s += Wl[c * RRv + d];
    wbar[idx] = s * (1.0f / DLv);
}

__global__ void k_softmax(const float* __restrict__ x, const int* __restrict__ mask,
                          float* __restrict__ qz) {
    int row = blockIdx.x;          // z*L + i
    int tid = threadIdx.x;         // 256 threads == DM
    float v = x[row * DMv + tid];
    int lane = tid & 63, wv = tid >> 6;
    __shared__ float sred[8];
    float m = v;
#pragma unroll
    for (int o = 32; o > 0; o >>= 1) m = fmaxf(m, __shfl_xor(m, o, 64));
    if (lane == 0) sred[wv] = m;
    __syncthreads();
    m = fmaxf(fmaxf(sred[0], sred[1]), fmaxf(sred[2], sred[3]));
    float e = __expf(v - m);
    float s = e;
#pragma unroll
    for (int o = 32; o > 0; o >>= 1) s += __shfl_xor(s, o, 64);
    if (lane == 0) sred[4 + wv] = s;
    __syncthreads();
    s = sred[4] + sred[5] + sred[6] + sred[7];
    float val = (mask[row] != 0) ? (e / s) : 0.0f;
    qz[row * DMv + tid] = val;
}

__global__ void k_colsum(const float* __restrict__ qz, float* __restrict__ t) {
    int z = blockIdx.x, b = threadIdx.x;
    const float* p = qz + z * LLv * DMv + b;
    float s = 0.f;
#pragma unroll 8
    for (int i = 0; i < LLv; ++i) s += p[i * DMv];
    t[z * DMv + b] = s;
}

// P[b][a] = sum_l sum_d V[l][b][d]*wbar[l][d]*U[l][a][d]   (C = A @ B^T, K=512)
__global__ __launch_bounds__(256) void k_pgemm(const float* __restrict__ U,
                                               const float* __restrict__ V,
                                               const float* __restrict__ wbar,
                                               float* __restrict__ P) {
    __shared__ float As[64][64 + 4];   // As[k][m]
    __shared__ float Bs[64][64 + 4];   // Bs[k][n]
    int tid = threadIdx.x;
    int bm = blockIdx.y * 64, bn = blockIdx.x * 64;
    int tx = tid & 15, ty = tid >> 4;
    float acc[4][4] = {};
    for (int k0 = 0; k0 < 512; k0 += 64) {
        int l = k0 >> 8;
        int d0 = k0 & 255;
        const float* Vl = V + l * DMv * RRv;
        const float* Ul = U + l * DMv * RRv;
        const float* wb = wbar + l * RRv + d0;
#pragma unroll
        for (int j = 0; j < 4; ++j) {
            int f = tid + j * 256;
            int row = f >> 4;            // 0..63
            int c4 = (f & 15) << 2;      // 0..60
            float4 av = *(const float4*)(Vl + (bm + row) * RRv + d0 + c4);
            float4 wv4 = *(const float4*)(wb + c4);
            As[c4 + 0][row] = av.x * wv4.x;
            As[c4 + 1][row] = av.y * wv4.y;
            As[c4 + 2][row] = av.z * wv4.z;
            As[c4 + 3][row] = av.w * wv4.w;
            float4 bv = *(const float4*)(Ul + (bn + row) * RRv + d0 + c4);
            Bs[c4 + 0][row] = bv.x;
            Bs[c4 + 1][row] = bv.y;
            Bs[c4 + 2][row] = bv.z;
            Bs[c4 + 3][row] = bv.w;
        }
        __syncthreads();
#pragma unroll
        for (int k = 0; k < 64; ++k) {
            float4 a = *(const float4*)&As[k][ty << 2];
            float4 b = *(const float4*)&Bs[k][tx << 2];
            acc[0][0] += a.x * b.x; acc[0][1] += a.x * b.y; acc[0][2] += a.x * b.z; acc[0][3] += a.x * b.w;
            acc[1][0] += a.y * b.x; acc[1][1] += a.y * b.y; acc[1][2] += a.y * b.z; acc[1][3] += a.y * b.w;
            acc[2][0] += a.z * b.x; acc[2][1] += a.z * b.y; acc[2][2] += a.z * b.z; acc[2][3] += a.z * b.w;
            acc[3][0] += a.w * b.x; acc[3][1] += a.w * b.y; acc[3][2] += a.w * b.z; acc[3][3] += a.w * b.w;
        }
        __syncthreads();
    }
#pragma unroll
    for (int i = 0; i < 4; ++i) {
        int r = bm + (ty << 2) + i;
#pragma unroll
        for (int j = 0; j < 4; ++j) {
            P[r * DMv + bn + (tx << 2) + j] = acc[i][j];
        }
    }
}

// out[r][a] = x[r][a] + valid[r] * sum_b (t[z][b]-qz[r][b]) * P[b][a]
__global__ __launch_bounds__(256) void k_final(const float* __restrict__ x,
                                               const int* __restrict__ mask,
                                               const float* __restrict__ qz,
                                               const float* __restrict__ t,
                                               const float* __restrict__ P,
                                               float* __restrict__ out) {
    __shared__ float As[64][64 + 4];   // As[k][m] = t[z][k] - qz[r][k]
    __shared__ float Bs[64][64 + 4];   // Bs[k][n] = P[k][bn+n]
    int tid = threadIdx.x;
    int bm = blockIdx.y * 64, bn = blockIdx.x * 64;
    int z = bm >> 8;                   // 64-row tile lies within one batch z
    int tx = tid & 15, ty = tid >> 4;
    float acc[4][4] = {};
    for (int k0 = 0; k0 < DMv; k0 += 64) {
#pragma unroll
        for (int j = 0; j < 4; ++j) {
            int f = tid + j * 256;
            int row = f >> 4;
            int c4 = (f & 15) << 2;
            float4 av = *(const float4*)(qz + (bm + row) * DMv + k0 + c4);
            float4 tv = *(const float4*)(t + z * DMv + k0 + c4);
            As[c4 + 0][row] = tv.x - av.x;
            As[c4 + 1][row] = tv.y - av.y;
            As[c4 + 2][row] = tv.z - av.z;
            As[c4 + 3][row] = tv.w - av.w;
            float4 bv = *(const float4*)(P + (k0 + row) * DMv + bn + c4);
            *(float4*)&Bs[row][c4] = bv;
        }
        __syncthreads();
#pragma unroll
        for (int k = 0; k < 64; ++k) {
            float4 a = *(const float4*)&As[k][ty << 2];
            float4 b = *(const float4*)&Bs[k][tx << 2];
            acc[0][0] += a.x * b.x; acc[0][1] += a.x * b.y; acc[0][2] += a.x * b.z; acc[0][3] += a.x * b.w;
            acc[1][0] += a.y * b.x; acc[1][1] += a.y * b.y; acc[1][2] += a.y * b.z; acc[1][3] += a.y * b.w;
            acc[2][0] += a.z * b.x; acc[2][1] += a.z * b.y; acc[2][2] += a.z * b.z; acc[2][3] += a.z * b.w;
            acc[3][0] += a.w * b.x; acc[3][1] += a.w * b.y; acc[3][2] += a.w * b.z; acc[3][3] += a.w * b.w;
        }
        __syncthreads();
    }
#pragma unroll
    for (int i = 0; i < 4; ++i) {
        int r = bm + (ty << 2) + i;
        float vld = (mask[r] != 0) ? 1.0f : 0.0f;
        int col = bn + (tx << 2);
        float4 xv = *(const float4*)(x + r * DMv + col);
        float4 ov;
        ov.x = xv.x + vld * acc[i][0];
        ov.y = xv.y + vld * acc[i][1];
        ov.z = xv.z + vld * acc[i][2];
        ov.w = xv.w + vld * acc[i][3];
        *(float4*)(out + r * DMv + col) = ov;
    }
}

extern "C" void kernel_launch(void* const* d_in, const int* in_sizes, int n_in,
                              void* d_out, int out_size, void* d_ws, size_t ws_size,
                              hipStream_t stream) {
    const float* x    = (const float*)d_in[0];   // (4,256,256)
    const float* U    = (const float*)d_in[1];   // (2,1,256,256)
    const float* V    = (const float*)d_in[2];   // (2,1,256,256)
    const float* W    = (const float*)d_in[3];   // (2,1,64,256)
    const int*   mask = (const int*)d_in[4];     // (4,256)
    float* out = (float*)d_out;                  // (4,256,256)

    float* qz   = (float*)d_ws;        // 262144 floats
    float* wbar = qz + 262144;         // 512
    float* t    = wbar + 512;          // 1024
    float* P    = t + 1024;            // 65536  (total ~1.3 MB of ws)

    hipLaunchKernelGGL(k_wbar,    dim3(2),     dim3(256), 0, stream, W, wbar);
    hipLaunchKernelGGL(k_softmax, dim3(1024),  dim3(256), 0, stream, x, mask, qz);
    hipLaunchKernelGGL(k_colsum,  dim3(4),     dim3(256), 0, stream, qz, t);
    hipLaunchKernelGGL(k_pgemm,   dim3(4, 4),  dim3(256), 0, stream, U, V, wbar, P);
    hipLaunchKernelGGL(k_final,   dim3(4, 16), dim3(256), 0, stream, x, mask, qz, t, P, out);
}

// Round 2
// 114.108 us; speedup vs baseline: 1.0022x; 1.0022x over previous
//
#include <hip/hip_runtime.h>

// Problem constants: B=4, L=256, DM=256, DL=64, R=256, K=1,
// N_ITER=4, STEPSIZE=1.0, DAMPING=0.0, REG=1.0.
//
// Algebraic collapse (verified exact in R1, absmax 0.0): with STEPSIZE=1 and
// DAMPING=0 the loop's cn_qz/cn_qy freeze at softmax(x) and uniform(1/64);
// every iteration produces the identical q_z = x + F. Output is ONE pass:
//   qz   = valid * softmax(x, -1)                       (B*L, DM)
//   t[z] = sum_i qz[z,i,:]                              (B, DM)
//   wbar[l,d] = mean_c W[l,c,d]                         (2, R)
//   P[b,a]   = sum_{l,d} V[l,b,d]*wbar[l,d]*U[l,a,d]    (DM, DM)
//   out[z,i,a] = x[z,i,a] + valid_i * sum_b (t[z,b]-qz[z,i,b]) * P[b,a]
//
// R2: fuse 5 dispatches -> 2. Kernel A = softmax (blocks 0..1023) + P-GEMM
// (blocks 1024..1039, wbar computed in-block). Kernel B = per-block redundant
// colsum t[z] into LDS + 64x64 output GEMM tile + epilogue.

#define DMv 256
#define LLv 256
#define RRv 256
#define DLv 64

__global__ __launch_bounds__(256) void k_fused_a(const float* __restrict__ x,
                                                 const int* __restrict__ mask,
                                                 const float* __restrict__ U,
                                                 const float* __restrict__ V,
                                                 const float* __restrict__ W,
                                                 float* __restrict__ qz,
                                                 float* __restrict__ P) {
    // 512 (wbar) + 2*64*68 (As,Bs) floats = 36352 B
    __shared__ float smem[512 + 2 * 64 * 68];
    int tid = threadIdx.x;
    int blk = blockIdx.x;

    if (blk < 1024) {
        // ---- softmax role: one row per block ----
        float* sred = smem;
        int row = blk;
        float v = x[row * DMv + tid];
        int lane = tid & 63, wv = tid >> 6;
        float m = v;
#pragma unroll
        for (int o = 32; o > 0; o >>= 1) m = fmaxf(m, __shfl_xor(m, o, 64));
        if (lane == 0) sred[wv] = m;
        __syncthreads();
        m = fmaxf(fmaxf(sred[0], sred[1]), fmaxf(sred[2], sred[3]));
        float e = __expf(v - m);
        float s = e;
#pragma unroll
        for (int o = 32; o > 0; o >>= 1) s += __shfl_xor(s, o, 64);
        if (lane == 0) sred[4 + wv] = s;
        __syncthreads();
        s = sred[4] + sred[5] + sred[6] + sred[7];
        qz[row * DMv + tid] = (mask[row] != 0) ? (e / s) : 0.0f;
        return;
    }

    // ---- P-GEMM role: P[b][a] = sum_l sum_d V[l][b][d]*wbar[l][d]*U[l][a][d]
    int pb = blk - 1024;                      // 0..15
    int bm = (pb >> 2) * 64, bn = (pb & 3) * 64;
    float* wb_s = smem;                       // [2][256]
    float (*As)[68] = (float (*)[68])(smem + 512);
    float (*Bs)[68] = (float (*)[68])(smem + 512 + 64 * 68);

    // wbar into LDS: thread tid computes wbar[l][tid] (coalesced over tid)
#pragma unroll
    for (int l = 0; l < 2; ++l) {
        const float* Wl = W + l * DLv * RRv;
        float s = 0.f;
#pragma unroll
        for (int c = 0; c < DLv; ++c) s += Wl[c * RRv + tid];
        wb_s[l * 256 + tid] = s * (1.0f / DLv);
    }
    __syncthreads();

    int tx = tid & 15, ty = tid >> 4;
    float acc[4][4] = {};
    for (int k0 = 0; k0 < 512; k0 += 64) {
        int l = k0 >> 8;
        int d0 = k0 & 255;
        const float* Vl = V + l * DMv * RRv;
        const float* Ul = U + l * DMv * RRv;
        const float* wb = wb_s + l * 256 + d0;
#pragma unroll
        for (int j = 0; j < 4; ++j) {
            int f = tid + j * 256;
            int row = f >> 4;            // 0..63
            int c4 = (f & 15) << 2;      // 0..60
            float4 av = *(const float4*)(Vl + (bm + row) * RRv + d0 + c4);
            As[c4 + 0][row] = av.x * wb[c4 + 0];
            As[c4 + 1][row] = av.y * wb[c4 + 1];
            As[c4 + 2][row] = av.z * wb[c4 + 2];
            As[c4 + 3][row] = av.w * wb[c4 + 3];
            float4 bv = *(const float4*)(Ul + (bn + row) * RRv + d0 + c4);
            Bs[c4 + 0][row] = bv.x;
            Bs[c4 + 1][row] = bv.y;
            Bs[c4 + 2][row] = bv.z;
            Bs[c4 + 3][row] = bv.w;
        }
        __syncthreads();
#pragma unroll
        for (int k = 0; k < 64; ++k) {
            float4 a = *(const float4*)&As[k][ty << 2];
            float4 b = *(const float4*)&Bs[k][tx << 2];
            acc[0][0] += a.x * b.x; acc[0][1] += a.x * b.y; acc[0][2] += a.x * b.z; acc[0][3] += a.x * b.w;
            acc[1][0] += a.y * b.x; acc[1][1] += a.y * b.y; acc[1][2] += a.y * b.z; acc[1][3] += a.y * b.w;
            acc[2][0] += a.z * b.x; acc[2][1] += a.z * b.y; acc[2][2] += a.z * b.z; acc[2][3] += a.z * b.w;
            acc[3][0] += a.w * b.x; acc[3][1] += a.w * b.y; acc[3][2] += a.w * b.z; acc[3][3] += a.w * b.w;
        }
        __syncthreads();
    }
#pragma unroll
    for (int i = 0; i < 4; ++i) {
        int r = bm + (ty << 2) + i;
#pragma unroll
        for (int j = 0; j < 4; ++j) {
            P[r * DMv + bn + (tx << 2) + j] = acc[i][j];
        }
    }
}

// out[r][a] = x[r][a] + valid[r] * sum_b (t[z][b]-qz[r][b]) * P[b][a]
// t computed redundantly per block (qz z-slice is 256 KB, L2-resident).
__global__ __launch_bounds__(256) void k_fused_b(const float* __restrict__ x,
                                                 const int* __restrict__ mask,
                                                 const float* __restrict__ qz,
                                                 const float* __restrict__ P,
                                                 float* __restrict__ out) {
    __shared__ float t_s[256];
    __shared__ float As[64][68];   // As[k][m] = t[z][k] - qz[r][k]
    __shared__ float Bs[64][68];   // Bs[k][n] = P[k][bn+n]
    int tid = threadIdx.x;
    int bm = blockIdx.y * 64, bn = blockIdx.x * 64;
    int z = bm >> 8;               // 64-row tile lies within one batch z

    // phase 1: t[z][tid] = colsum of qz z-slice (coalesced across tid)
    {
        const float* qzz = qz + z * LLv * DMv + tid;
        float s = 0.f;
#pragma unroll 16
        for (int i = 0; i < LLv; ++i) s += qzz[i * DMv];
        t_s[tid] = s;
    }
    __syncthreads();

    // phase 2: 64x64 GEMM tile
    int tx = tid & 15, ty = tid >> 4;
    float acc[4][4] = {};
    for (int k0 = 0; k0 < DMv; k0 += 64) {
#pragma unroll
        for (int j = 0; j < 4; ++j) {
            int f = tid + j * 256;
            int row = f >> 4;
            int c4 = (f & 15) << 2;
            float4 av = *(const float4*)(qz + (bm + row) * DMv + k0 + c4);
            As[c4 + 0][row] = t_s[k0 + c4 + 0] - av.x;
            As[c4 + 1][row] = t_s[k0 + c4 + 1] - av.y;
            As[c4 + 2][row] = t_s[k0 + c4 + 2] - av.z;
            As[c4 + 3][row] = t_s[k0 + c4 + 3] - av.w;
            float4 bv = *(const float4*)(P + (k0 + row) * DMv + bn + c4);
            *(float4*)&Bs[row][c4] = bv;
        }
        __syncthreads();
#pragma unroll
        for (int k = 0; k < 64; ++k) {
            float4 a = *(const float4*)&As[k][ty << 2];
            float4 b = *(const float4*)&Bs[k][tx << 2];
            acc[0][0] += a.x * b.x; acc[0][1] += a.x * b.y; acc[0][2] += a.x * b.z; acc[0][3] += a.x * b.w;
            acc[1][0] += a.y * b.x; acc[1][1] += a.y * b.y; acc[1][2] += a.y * b.z; acc[1][3] += a.y * b.w;
            acc[2][0] += a.z * b.x; acc[2][1] += a.z * b.y; acc[2][2] += a.z * b.z; acc[2][3] += a.z * b.w;
            acc[3][0] += a.w * b.x; acc[3][1] += a.w * b.y; acc[3][2] += a.w * b.z; acc[3][3] += a.w * b.w;
        }
        __syncthreads();
    }
#pragma unroll
    for (int i = 0; i < 4; ++i) {
        int r = bm + (ty << 2) + i;
        float vld = (mask[r] != 0) ? 1.0f : 0.0f;
        int col = bn + (tx << 2);
        float4 xv = *(const float4*)(x + r * DMv + col);
        float4 ov;
        ov.x = xv.x + vld * acc[i][0];
        ov.y = xv.y + vld * acc[i][1];
        ov.z = xv.z + vld * acc[i][2];
        ov.w = xv.w + vld * acc[i][3];
        *(float4*)(out + r * DMv + col) = ov;
    }
}

extern "C" void kernel_launch(void* const* d_in, const int* in_sizes, int n_in,
                              void* d_out, int out_size, void* d_ws, size_t ws_size,
                              hipStream_t stream) {
    const float* x    = (const float*)d_in[0];   // (4,256,256)
    const float* U    = (const float*)d_in[1];   // (2,1,256,256)
    const float* V    = (const float*)d_in[2];   // (2,1,256,256)
    const float* W    = (const float*)d_in[3];   // (2,1,64,256)
    const int*   mask = (const int*)d_in[4];     // (4,256)
    float* out = (float*)d_out;                  // (4,256,256)

    float* qz = (float*)d_ws;          // 262144 floats
    float* P  = qz + 262144;           // 65536 floats

    hipLaunchKernelGGL(k_fused_a, dim3(1040),  dim3(256), 0, stream,
                       x, mask, U, V, W, qz, P);
    hipLaunchKernelGGL(k_fused_b, dim3(4, 16), dim3(256), 0, stream,
                       x, mask, qz, P, out);
}